// Round 1
// baseline (529.110 us; speedup 1.0000x reference)
//
#include <hip/hip_runtime.h>

#define N_NODES 50000
#define N_EDGES 800000
#define IN_CH 128
#define HID 64
#define HID2 32
#define BN_EPS 1e-5f

// ---------- degree / dinv ----------
__global__ __launch_bounds__(256) void k_deg(const int* __restrict__ ei, int* __restrict__ deg, int E) {
    int e = blockIdx.x * 256 + threadIdx.x;
    if (e < E) atomicAdd(&deg[ei[E + e]], 1);
}

__global__ __launch_bounds__(256) void k_dinv(const int* __restrict__ deg, float* __restrict__ dinv, int N) {
    int i = blockIdx.x * 256 + threadIdx.x;
    if (i < N) dinv[i] = rsqrtf((float)deg[i] + 1.0f);  // +1 = self loop
}

// ---------- GEMM1: h1p[n][f] = dinv[n] * sum_k x[n][k]*W1[k][f] ----------
// 32 nodes x 64 f per block; W1 (128x64, 32KB) staged in LDS.
__global__ __launch_bounds__(256) void k_gemm1(const float* __restrict__ x, const float* __restrict__ W1,
                                               const float* __restrict__ dinv, float* __restrict__ h1p, int N) {
    __shared__ float W1s[IN_CH * HID];
    int tid = threadIdx.x;
    {
        const float4* W1v = (const float4*)W1;
        float4* W1sv = (float4*)W1s;
#pragma unroll
        for (int i = 0; i < 8; ++i) W1sv[tid + 256 * i] = W1v[tid + 256 * i];
    }
    __syncthreads();
    int f = tid & 63, g = tid >> 6;          // g uniform per wave
    int n0 = blockIdx.x * 32 + g * 8;
    float acc[8] = {0.f, 0.f, 0.f, 0.f, 0.f, 0.f, 0.f, 0.f};
    for (int k = 0; k < IN_CH; k += 4) {
        float4 xv[8];
#pragma unroll
        for (int i = 0; i < 8; ++i) {
            int n = n0 + i; if (n > N - 1) n = N - 1;   // clamp, skip store later
            xv[i] = *(const float4*)&x[(size_t)n * IN_CH + k];
        }
        float w0 = W1s[(k + 0) * HID + f];
        float w1 = W1s[(k + 1) * HID + f];
        float w2 = W1s[(k + 2) * HID + f];
        float w3 = W1s[(k + 3) * HID + f];
#pragma unroll
        for (int i = 0; i < 8; ++i) {
            acc[i] = fmaf(xv[i].x, w0, acc[i]);
            acc[i] = fmaf(xv[i].y, w1, acc[i]);
            acc[i] = fmaf(xv[i].z, w2, acc[i]);
            acc[i] = fmaf(xv[i].w, w3, acc[i]);
        }
    }
#pragma unroll
    for (int i = 0; i < 8; ++i) {
        int n = n0 + i;
        if (n < N) h1p[(size_t)n * HID + f] = acc[i] * dinv[n];
    }
}

// ---------- GEMM2: h2p[n][f] = dinv[n] * sum_k in[n][k]*W2[k][f] ----------
// 64 nodes x 32 f per block; W2 (64x32, 8KB) in LDS.
__global__ __launch_bounds__(256) void k_gemm2(const float* __restrict__ in, const float* __restrict__ W2,
                                               const float* __restrict__ dinv, float* __restrict__ h2p, int N) {
    __shared__ float W2s[HID * HID2];
    int tid = threadIdx.x;
    {
        const float4* W2v = (const float4*)W2;
        float4* W2sv = (float4*)W2s;
#pragma unroll
        for (int i = 0; i < 2; ++i) W2sv[tid + 256 * i] = W2v[tid + 256 * i];
    }
    __syncthreads();
    int f = tid & 31, g = tid >> 5;          // half-wave groups
    int n0 = blockIdx.x * 64 + g * 8;
    float acc[8] = {0.f, 0.f, 0.f, 0.f, 0.f, 0.f, 0.f, 0.f};
    for (int k = 0; k < HID; k += 4) {
        float4 xv[8];
#pragma unroll
        for (int i = 0; i < 8; ++i) {
            int n = n0 + i; if (n > N - 1) n = N - 1;
            xv[i] = *(const float4*)&in[(size_t)n * HID + k];
        }
        float w0 = W2s[(k + 0) * HID2 + f];
        float w1 = W2s[(k + 1) * HID2 + f];
        float w2 = W2s[(k + 2) * HID2 + f];
        float w3 = W2s[(k + 3) * HID2 + f];
#pragma unroll
        for (int i = 0; i < 8; ++i) {
            acc[i] = fmaf(xv[i].x, w0, acc[i]);
            acc[i] = fmaf(xv[i].y, w1, acc[i]);
            acc[i] = fmaf(xv[i].z, w2, acc[i]);
            acc[i] = fmaf(xv[i].w, w3, acc[i]);
        }
    }
#pragma unroll
    for (int i = 0; i < 8; ++i) {
        int n = n0 + i;
        if (n < N) h2p[(size_t)n * HID2 + f] = acc[i] * dinv[n];
    }
}

// ---------- edge scatter: acc[col][f] += hp[row][f] ----------
template <int LOGF>
__global__ __launch_bounds__(256) void k_scatter(const int* __restrict__ ei, const float* __restrict__ hp,
                                                 float* __restrict__ acc, int E) {
    int t = blockIdx.x * 256 + threadIdx.x;
    int e = t >> LOGF;
    if (e >= E) return;
    int f = t & ((1 << LOGF) - 1);
    int r = ei[e], c = ei[E + e];            // wave-uniform scalar loads
    atomicAdd(&acc[((size_t)c << LOGF) + f], hp[((size_t)r << LOGF) + f]);
}

// ---------- finalize layer 1: bias + BN(eval) + ReLU, in-place into acc1 ----------
__global__ __launch_bounds__(256) void k_fin1(const float* __restrict__ h1p, float* __restrict__ acc1,
                                              const float* __restrict__ dinv, const float* __restrict__ b1,
                                              const float* __restrict__ g1, const float* __restrict__ be1,
                                              const float* __restrict__ rm1, const float* __restrict__ rv1, int N) {
    int t = blockIdx.x * 256 + threadIdx.x;   // t < N*64 exactly
    int n = t >> 6, f = t & 63;
    float v = dinv[n] * (acc1[t] + h1p[t]) + b1[f];
    float s = g1[f] * rsqrtf(rv1[f] + BN_EPS);
    v = (v - rm1[f]) * s + be1[f];
    acc1[t] = fmaxf(v, 0.f);
}

// ---------- finalize layer 2 + FC: out[n] = sum_f relu(bn(...))[f]*fcW[f] + fcb ----------
__global__ __launch_bounds__(256) void k_fin2(const float* __restrict__ h2p, const float* __restrict__ acc2,
                                              const float* __restrict__ dinv, const float* __restrict__ b2,
                                              const float* __restrict__ g2, const float* __restrict__ be2,
                                              const float* __restrict__ rm2, const float* __restrict__ rv2,
                                              const float* __restrict__ fcW, const float* __restrict__ fcb,
                                              float* __restrict__ out, int N) {
    int t = blockIdx.x * 256 + threadIdx.x;   // t < N*32 exactly
    int n = t >> 5, f = t & 31;
    int idx = (n << 5) + f;
    float v = dinv[n] * (acc2[idx] + h2p[idx]) + b2[f];
    float s = g2[f] * rsqrtf(rv2[f] + BN_EPS);
    v = (v - rm2[f]) * s + be2[f];
    v = fmaxf(v, 0.f) * fcW[f];
    // reduce across the 32-lane half-wave
#pragma unroll
    for (int o = 16; o > 0; o >>= 1) v += __shfl_down(v, o, 32);
    if (f == 0) out[n] = v + fcb[0];
}

extern "C" void kernel_launch(void* const* d_in, const int* in_sizes, int n_in,
                              void* d_out, int out_size, void* d_ws, size_t ws_size,
                              hipStream_t stream) {
    const float* x   = (const float*)d_in[0];
    const int*   ei  = (const int*)d_in[1];
    const float* W1  = (const float*)d_in[2];
    const float* b1  = (const float*)d_in[3];
    const float* W2  = (const float*)d_in[4];
    const float* b2  = (const float*)d_in[5];
    const float* fcW = (const float*)d_in[6];
    const float* fcb = (const float*)d_in[7];
    const float* g1  = (const float*)d_in[8];
    const float* be1 = (const float*)d_in[9];
    const float* rm1 = (const float*)d_in[10];
    const float* rv1 = (const float*)d_in[11];
    const float* g2  = (const float*)d_in[12];
    const float* be2 = (const float*)d_in[13];
    const float* rm2 = (const float*)d_in[14];
    const float* rv2 = (const float*)d_in[15];
    float* out = (float*)d_out;

    const int N = N_NODES, E = N_EDGES;
    float* ws = (float*)d_ws;
    const size_t NP = 50176;                 // N rounded up, 256-aligned
    int*   deg  = (int*)ws;                  // N ints
    float* dinv = ws + NP;                   // N floats
    float* h1p  = ws + 2 * NP;               // N*64
    float* h2p  = h1p + (size_t)N * HID;     // N*32
    float* acc1 = h2p + (size_t)N * HID2;    // N*64
    float* acc2 = acc1 + (size_t)N * HID;    // N*32  (acc1|acc2 contiguous)

    hipMemsetAsync(deg, 0, (size_t)N * sizeof(int), stream);
    hipMemsetAsync(acc1, 0, (size_t)N * (HID + HID2) * sizeof(float), stream);

    k_deg<<<(E + 255) / 256, 256, 0, stream>>>(ei, deg, E);
    k_dinv<<<(N + 255) / 256, 256, 0, stream>>>(deg, dinv, N);

    k_gemm1<<<(N + 31) / 32, 256, 0, stream>>>(x, W1, dinv, h1p, N);
    k_scatter<6><<<(E * 64) / 256, 256, 0, stream>>>(ei, h1p, acc1, E);
    k_fin1<<<(N * HID) / 256, 256, 0, stream>>>(h1p, acc1, dinv, b1, g1, be1, rm1, rv1, N);

    k_gemm2<<<(N + 63) / 64, 256, 0, stream>>>(acc1, W2, dinv, h2p, N);
    k_scatter<5><<<(E * 32) / 256, 256, 0, stream>>>(ei, h2p, acc2, E);
    k_fin2<<<(N * HID2) / 256, 256, 0, stream>>>(h2p, acc2, dinv, b2, g2, be2, rm2, rv2, fcW, fcb, out, N);
}

// Round 2
// 351.683 us; speedup vs baseline: 1.5045x; 1.5045x over previous
//
#include <hip/hip_runtime.h>

#define N_NODES 50000
#define N_EDGES 800000
#define IN_CH 128
#define HID 64
#define HID2 32
#define BN_EPS 1e-5f

// ---------- degree ----------
__global__ __launch_bounds__(256) void k_deg(const int* __restrict__ ei, int* __restrict__ deg, int E) {
    int e = blockIdx.x * 256 + threadIdx.x;
    if (e < E) atomicAdd(&deg[ei[E + e]], 1);
}

__global__ __launch_bounds__(256) void k_dinv(const int* __restrict__ deg, float* __restrict__ dinv, int N) {
    int i = blockIdx.x * 256 + threadIdx.x;
    if (i < N) dinv[i] = rsqrtf((float)deg[i] + 1.0f);  // +1 = self loop
}

// ---------- exclusive scan of deg -> offs (3 tiny kernels) ----------
__global__ __launch_bounds__(256) void k_scan1(const int* __restrict__ deg, int* __restrict__ bsum, int N) {
    __shared__ int s[256];
    int i = blockIdx.x * 256 + threadIdx.x;
    s[threadIdx.x] = (i < N) ? deg[i] : 0;
    __syncthreads();
    for (int off = 128; off > 0; off >>= 1) {
        if (threadIdx.x < off) s[threadIdx.x] += s[threadIdx.x + off];
        __syncthreads();
    }
    if (threadIdx.x == 0) bsum[blockIdx.x] = s[0];
}

__global__ __launch_bounds__(256) void k_scan2(const int* __restrict__ bsum, int* __restrict__ bofs,
                                               int* __restrict__ offs, int NB, int N) {
    __shared__ int s[256];
    int t = threadIdx.x;
    int v = (t < NB) ? bsum[t] : 0;
    s[t] = v; __syncthreads();
    for (int off = 1; off < 256; off <<= 1) {
        int u = (t >= off) ? s[t - off] : 0;
        __syncthreads(); s[t] += u; __syncthreads();
    }
    if (t < NB) bofs[t] = s[t] - v;          // exclusive
    if (t == NB - 1) offs[N] = s[t];         // total == E
}

__global__ __launch_bounds__(256) void k_scan3(const int* __restrict__ deg, const int* __restrict__ bofs,
                                               int* __restrict__ offs, int* __restrict__ cursor, int N) {
    __shared__ int s[256];
    int i = blockIdx.x * 256 + threadIdx.x, t = threadIdx.x;
    int v = (i < N) ? deg[i] : 0;
    s[t] = v; __syncthreads();
    for (int off = 1; off < 256; off <<= 1) {
        int u = (t >= off) ? s[t - off] : 0;
        __syncthreads(); s[t] += u; __syncthreads();
    }
    if (i < N) {
        int ex = bofs[blockIdx.x] + s[t] - v;
        offs[i] = ex; cursor[i] = ex;
    }
}

// ---------- CSR fill: csr[offs[c]..] = row ids of incoming edges ----------
__global__ __launch_bounds__(256) void k_fill(const int* __restrict__ ei, int* __restrict__ cursor,
                                              int* __restrict__ csr, int E) {
    int e = blockIdx.x * 256 + threadIdx.x;
    if (e >= E) return;
    int r = ei[e], c = ei[E + e];
    int pos = atomicAdd(&cursor[c], 1);
    csr[pos] = r;
}

// ---------- GEMM1: h1p[n][f] = dinv[n] * sum_k x[n][k]*W1[k][f] ----------
__global__ __launch_bounds__(256) void k_gemm1(const float* __restrict__ x, const float* __restrict__ W1,
                                               const float* __restrict__ dinv, float* __restrict__ h1p, int N) {
    __shared__ float W1s[IN_CH * HID];
    int tid = threadIdx.x;
    {
        const float4* W1v = (const float4*)W1;
        float4* W1sv = (float4*)W1s;
#pragma unroll
        for (int i = 0; i < 8; ++i) W1sv[tid + 256 * i] = W1v[tid + 256 * i];
    }
    __syncthreads();
    int f = tid & 63, g = tid >> 6;
    int n0 = blockIdx.x * 32 + g * 8;
    float acc[8] = {0.f, 0.f, 0.f, 0.f, 0.f, 0.f, 0.f, 0.f};
    for (int k = 0; k < IN_CH; k += 4) {
        float4 xv[8];
#pragma unroll
        for (int i = 0; i < 8; ++i) {
            int n = n0 + i; if (n > N - 1) n = N - 1;
            xv[i] = *(const float4*)&x[(size_t)n * IN_CH + k];
        }
        float w0 = W1s[(k + 0) * HID + f];
        float w1 = W1s[(k + 1) * HID + f];
        float w2 = W1s[(k + 2) * HID + f];
        float w3 = W1s[(k + 3) * HID + f];
#pragma unroll
        for (int i = 0; i < 8; ++i) {
            acc[i] = fmaf(xv[i].x, w0, acc[i]);
            acc[i] = fmaf(xv[i].y, w1, acc[i]);
            acc[i] = fmaf(xv[i].z, w2, acc[i]);
            acc[i] = fmaf(xv[i].w, w3, acc[i]);
        }
    }
#pragma unroll
    for (int i = 0; i < 8; ++i) {
        int n = n0 + i;
        if (n < N) h1p[(size_t)n * HID + f] = acc[i] * dinv[n];
    }
}

// ---------- GEMM2: h2p[n][f] = dinv[n] * sum_k in[n][k]*W2[k][f] ----------
__global__ __launch_bounds__(256) void k_gemm2(const float* __restrict__ in, const float* __restrict__ W2,
                                               const float* __restrict__ dinv, float* __restrict__ h2p, int N) {
    __shared__ float W2s[HID * HID2];
    int tid = threadIdx.x;
    {
        const float4* W2v = (const float4*)W2;
        float4* W2sv = (float4*)W2s;
#pragma unroll
        for (int i = 0; i < 2; ++i) W2sv[tid + 256 * i] = W2v[tid + 256 * i];
    }
    __syncthreads();
    int f = tid & 31, g = tid >> 5;
    int n0 = blockIdx.x * 64 + g * 8;
    float acc[8] = {0.f, 0.f, 0.f, 0.f, 0.f, 0.f, 0.f, 0.f};
    for (int k = 0; k < HID; k += 4) {
        float4 xv[8];
#pragma unroll
        for (int i = 0; i < 8; ++i) {
            int n = n0 + i; if (n > N - 1) n = N - 1;
            xv[i] = *(const float4*)&in[(size_t)n * HID + k];
        }
        float w0 = W2s[(k + 0) * HID2 + f];
        float w1 = W2s[(k + 1) * HID2 + f];
        float w2 = W2s[(k + 2) * HID2 + f];
        float w3 = W2s[(k + 3) * HID2 + f];
#pragma unroll
        for (int i = 0; i < 8; ++i) {
            acc[i] = fmaf(xv[i].x, w0, acc[i]);
            acc[i] = fmaf(xv[i].y, w1, acc[i]);
            acc[i] = fmaf(xv[i].z, w2, acc[i]);
            acc[i] = fmaf(xv[i].w, w3, acc[i]);
        }
    }
#pragma unroll
    for (int i = 0; i < 8; ++i) {
        int n = n0 + i;
        if (n < N) h2p[(size_t)n * HID2 + f] = acc[i] * dinv[n];
    }
}

// ---------- gather layer 1 (one wave per node, lane = feature) + BN + ReLU ----------
__global__ __launch_bounds__(256) void k_gather1(const float* __restrict__ h1p, const int* __restrict__ offs,
                                                 const int* __restrict__ csr, const float* __restrict__ dinv,
                                                 const float* __restrict__ b1, const float* __restrict__ g1,
                                                 const float* __restrict__ be1, const float* __restrict__ rm1,
                                                 const float* __restrict__ rv1, float* __restrict__ hact, int N) {
    int w = (blockIdx.x * 256 + threadIdx.x) >> 6;
    int lane = threadIdx.x & 63;
    if (w >= N) return;
    int start = offs[w], end = offs[w + 1];
    float acc = h1p[((size_t)w << 6) + lane];   // self loop
    for (int j = start; j < end; j += 64) {
        int cnt = end - j; if (cnt > 64) cnt = 64;
        int rid = (j + lane < end) ? csr[j + lane] : 0;
        int t = 0;
        for (; t + 3 < cnt; t += 4) {
            int r0 = __shfl(rid, t, 64), r1 = __shfl(rid, t + 1, 64);
            int r2 = __shfl(rid, t + 2, 64), r3 = __shfl(rid, t + 3, 64);
            float a0 = h1p[((size_t)r0 << 6) + lane];
            float a1 = h1p[((size_t)r1 << 6) + lane];
            float a2 = h1p[((size_t)r2 << 6) + lane];
            float a3 = h1p[((size_t)r3 << 6) + lane];
            acc += (a0 + a1) + (a2 + a3);
        }
        for (; t < cnt; ++t) {
            int r = __shfl(rid, t, 64);
            acc += h1p[((size_t)r << 6) + lane];
        }
    }
    float v = dinv[w] * acc + b1[lane];
    v = (v - rm1[lane]) * (g1[lane] * rsqrtf(rv1[lane] + BN_EPS)) + be1[lane];
    hact[((size_t)w << 6) + lane] = fmaxf(v, 0.f);
}

// ---------- gather layer 2 (half-wave per node) + BN + ReLU + FC ----------
__global__ __launch_bounds__(256) void k_gather2(const float* __restrict__ h2p, const int* __restrict__ offs,
                                                 const int* __restrict__ csr, const float* __restrict__ dinv,
                                                 const float* __restrict__ b2, const float* __restrict__ g2,
                                                 const float* __restrict__ be2, const float* __restrict__ rm2,
                                                 const float* __restrict__ rv2, const float* __restrict__ fcW,
                                                 const float* __restrict__ fcb, float* __restrict__ out, int N) {
    int h = (blockIdx.x * 256 + threadIdx.x) >> 5;
    int lane = threadIdx.x & 31;
    if (h >= N) return;
    int start = offs[h], end = offs[h + 1];
    float acc = h2p[((size_t)h << 5) + lane];   // self loop
    for (int j = start; j < end; j += 32) {
        int cnt = end - j; if (cnt > 32) cnt = 32;
        int rid = (j + lane < end) ? csr[j + lane] : 0;
        int t = 0;
        for (; t + 3 < cnt; t += 4) {
            int r0 = __shfl(rid, t, 32), r1 = __shfl(rid, t + 1, 32);
            int r2 = __shfl(rid, t + 2, 32), r3 = __shfl(rid, t + 3, 32);
            float a0 = h2p[((size_t)r0 << 5) + lane];
            float a1 = h2p[((size_t)r1 << 5) + lane];
            float a2 = h2p[((size_t)r2 << 5) + lane];
            float a3 = h2p[((size_t)r3 << 5) + lane];
            acc += (a0 + a1) + (a2 + a3);
        }
        for (; t < cnt; ++t) {
            int r = __shfl(rid, t, 32);
            acc += h2p[((size_t)r << 5) + lane];
        }
    }
    float v = dinv[h] * acc + b2[lane];
    v = (v - rm2[lane]) * (g2[lane] * rsqrtf(rv2[lane] + BN_EPS)) + be2[lane];
    v = fmaxf(v, 0.f) * fcW[lane];
#pragma unroll
    for (int o = 16; o > 0; o >>= 1) v += __shfl_down(v, o, 32);
    if (lane == 0) out[h] = v + fcb[0];
}

extern "C" void kernel_launch(void* const* d_in, const int* in_sizes, int n_in,
                              void* d_out, int out_size, void* d_ws, size_t ws_size,
                              hipStream_t stream) {
    const float* x   = (const float*)d_in[0];
    const int*   ei  = (const int*)d_in[1];
    const float* W1  = (const float*)d_in[2];
    const float* b1  = (const float*)d_in[3];
    const float* W2  = (const float*)d_in[4];
    const float* b2  = (const float*)d_in[5];
    const float* fcW = (const float*)d_in[6];
    const float* fcb = (const float*)d_in[7];
    const float* g1  = (const float*)d_in[8];
    const float* be1 = (const float*)d_in[9];
    const float* rm1 = (const float*)d_in[10];
    const float* rv1 = (const float*)d_in[11];
    const float* g2  = (const float*)d_in[12];
    const float* be2 = (const float*)d_in[13];
    const float* rm2 = (const float*)d_in[14];
    const float* rv2 = (const float*)d_in[15];
    float* out = (float*)d_out;

    const int N = N_NODES, E = N_EDGES;
    const int NB = (N + 255) / 256;          // 196 scan blocks

    // workspace layout (byte offsets, 256-aligned)
    char* base = (char*)d_ws;
    int*   deg    = (int*)(base);                        // N ints       (200704 B)
    int*   offs   = (int*)(base + 200704);               // N+1 ints     (200704 B)
    int*   cursor = (int*)(base + 2 * 200704);           // N ints       (200704 B)
    float* dinv   = (float*)(base + 3 * 200704);         // N floats     (200704 B)
    int*   bsum   = (int*)(base + 4 * 200704);           // 256 ints
    int*   bofs   = (int*)(base + 4 * 200704 + 1024);    // 256 ints
    int*   csr    = (int*)(base + 4 * 200704 + 2048);    // E ints       (3.2 MB)
    float* h1p    = (float*)(base + 4 * 200704 + 2048 + 3200000);            // N*64 floats (12.8 MB)
    float* hact   = (float*)(base + 4 * 200704 + 2048 + 3200000 + 12800000); // N*64 floats (12.8 MB)
    float* h2p    = h1p;   // reuse: h1p dead after gather1

    hipMemsetAsync(deg, 0, (size_t)N * sizeof(int), stream);

    k_deg  <<<(E + 255) / 256, 256, 0, stream>>>(ei, deg, E);
    k_dinv <<<NB, 256, 0, stream>>>(deg, dinv, N);
    k_scan1<<<NB, 256, 0, stream>>>(deg, bsum, N);
    k_scan2<<<1, 256, 0, stream>>>(bsum, bofs, offs, NB, N);
    k_scan3<<<NB, 256, 0, stream>>>(deg, bofs, offs, cursor, N);
    k_fill <<<(E + 255) / 256, 256, 0, stream>>>(ei, cursor, csr, E);

    k_gemm1  <<<(N + 31) / 32, 256, 0, stream>>>(x, W1, dinv, h1p, N);
    k_gather1<<<(N * 64) / 256, 256, 0, stream>>>(h1p, offs, csr, dinv, b1, g1, be1, rm1, rv1, hact, N);
    k_gemm2  <<<(N + 63) / 64, 256, 0, stream>>>(hact, W2, dinv, h2p, N);
    k_gather2<<<(N * 32) / 256, 256, 0, stream>>>(h2p, offs, csr, dinv, b2, g2, be2, rm2, rv2, fcW, fcb, out, N);
}

// Round 3
// 319.045 us; speedup vs baseline: 1.6584x; 1.1023x over previous
//
#include <hip/hip_runtime.h>

#define N_NODES 50000
#define N_EDGES 800000
#define IN_CH 128
#define HID 64
#define HID2 32
#define BN_EPS 1e-5f

// ---------- degree ----------
__global__ __launch_bounds__(256) void k_deg(const int* __restrict__ ei, int* __restrict__ deg, int E) {
    int e = blockIdx.x * 256 + threadIdx.x;
    if (e < E) atomicAdd(&deg[ei[E + e]], 1);
}

// ---------- scan stage 1 (block sums) + dinv ----------
__global__ __launch_bounds__(256) void k_scan1(const int* __restrict__ deg, int* __restrict__ bsum,
                                               float* __restrict__ dinv, int N) {
    __shared__ int s[256];
    int i = blockIdx.x * 256 + threadIdx.x;
    int d = (i < N) ? deg[i] : 0;
    if (i < N) dinv[i] = rsqrtf((float)d + 1.0f);  // +1 = self loop
    s[threadIdx.x] = d;
    __syncthreads();
    for (int off = 128; off > 0; off >>= 1) {
        if (threadIdx.x < off) s[threadIdx.x] += s[threadIdx.x + off];
        __syncthreads();
    }
    if (threadIdx.x == 0) bsum[blockIdx.x] = s[0];
}

__global__ __launch_bounds__(256) void k_scan2(const int* __restrict__ bsum, int* __restrict__ bofs,
                                               int* __restrict__ offs, int NB, int N) {
    __shared__ int s[256];
    int t = threadIdx.x;
    int v = (t < NB) ? bsum[t] : 0;
    s[t] = v; __syncthreads();
    for (int off = 1; off < 256; off <<= 1) {
        int u = (t >= off) ? s[t - off] : 0;
        __syncthreads(); s[t] += u; __syncthreads();
    }
    if (t < NB) bofs[t] = s[t] - v;          // exclusive
    if (t == NB - 1) offs[N] = s[t];         // total == E
}

__global__ __launch_bounds__(256) void k_scan3(const int* __restrict__ deg, const int* __restrict__ bofs,
                                               int* __restrict__ offs, int* __restrict__ cursor, int N) {
    __shared__ int s[256];
    int i = blockIdx.x * 256 + threadIdx.x, t = threadIdx.x;
    int v = (i < N) ? deg[i] : 0;
    s[t] = v; __syncthreads();
    for (int off = 1; off < 256; off <<= 1) {
        int u = (t >= off) ? s[t - off] : 0;
        __syncthreads(); s[t] += u; __syncthreads();
    }
    if (i < N) {
        int ex = bofs[blockIdx.x] + s[t] - v;
        offs[i] = ex; cursor[i] = ex;
    }
}

// ---------- CSR fill ----------
__global__ __launch_bounds__(256) void k_fill(const int* __restrict__ ei, int* __restrict__ cursor,
                                              int* __restrict__ csr, int E) {
    int e = blockIdx.x * 256 + threadIdx.x;
    if (e >= E) return;
    int r = ei[e], c = ei[E + e];
    int pos = atomicAdd(&cursor[c], 1);
    csr[pos] = r;
}

// ---------- GEMM: outp[n][f] = dinv[n] * sum_k in[n][k]*W[k][f] ----------
// No LDS. Manual 1-deep register prefetch; #pragma unroll 1 prevents the
// full-K unroll that spilled (round 2: gemm2 at 256 VGPRs, 68 MB scratch).
template <int KD, int FD>
__global__ __launch_bounds__(256) void k_gemm(const float* __restrict__ in, const float* __restrict__ W,
                                              const float* __restrict__ dinv, float* __restrict__ outp, int N) {
    int tid = threadIdx.x;
    int f = tid & (FD - 1), g = tid / FD;               // 8 nodes per group
    int n0 = blockIdx.x * ((256 / FD) * 8) + g * 8;
    int off[8];
#pragma unroll
    for (int i = 0; i < 8; ++i) {
        int n = n0 + i; if (n > N - 1) n = N - 1;       // clamp; store masked below
        off[i] = n * KD;
    }
    float acc[8] = {0.f, 0.f, 0.f, 0.f, 0.f, 0.f, 0.f, 0.f};
    float4 xv[8]; float wv[4];
#pragma unroll
    for (int i = 0; i < 8; ++i) xv[i] = *(const float4*)(in + off[i]);
#pragma unroll
    for (int j = 0; j < 4; ++j) wv[j] = W[j * FD + f];
#pragma unroll 1
    for (int k = 0; k < KD; k += 4) {
        int kn = (k + 4 < KD) ? k + 4 : 0;              // dummy reload on last iter
        float4 xn[8]; float wn[4];
#pragma unroll
        for (int i = 0; i < 8; ++i) xn[i] = *(const float4*)(in + off[i] + kn);
#pragma unroll
        for (int j = 0; j < 4; ++j) wn[j] = W[(kn + j) * FD + f];
#pragma unroll
        for (int i = 0; i < 8; ++i) {
            acc[i] = fmaf(xv[i].x, wv[0], acc[i]);
            acc[i] = fmaf(xv[i].y, wv[1], acc[i]);
            acc[i] = fmaf(xv[i].z, wv[2], acc[i]);
            acc[i] = fmaf(xv[i].w, wv[3], acc[i]);
        }
#pragma unroll
        for (int i = 0; i < 8; ++i) xv[i] = xn[i];
#pragma unroll
        for (int j = 0; j < 4; ++j) wv[j] = wn[j];
    }
#pragma unroll
    for (int i = 0; i < 8; ++i) {
        int n = n0 + i;
        if (n < N) outp[(size_t)n * FD + f] = acc[i] * dinv[n];
    }
}

// ---------- gather layer 1: 4 nodes/wave, lane owns 4 features (float4) ----------
__global__ __launch_bounds__(256) void k_gather1(const float* __restrict__ h1p, const int* __restrict__ offs,
                                                 const int* __restrict__ csr, const float* __restrict__ dinv,
                                                 const float* __restrict__ b1, const float* __restrict__ g1,
                                                 const float* __restrict__ be1, const float* __restrict__ rm1,
                                                 const float* __restrict__ rv1, float* __restrict__ hact, int N) {
    int wid = (blockIdx.x * 256 + threadIdx.x) >> 6;
    int lane = threadIdx.x & 63;
    int sub = lane >> 4;              // node slot 0..3
    int l16 = lane & 15;
    int fl = l16 << 2;                // feature base
    int nd0 = wid * 4 + sub;
    int nd = (nd0 < N) ? nd0 : N - 1;
    int start = offs[nd], end = offs[nd + 1];
    float4 acc = *(const float4*)(h1p + ((size_t)nd << 6) + fl);   // self loop
    int sb = sub << 4;
    for (int j = start; j < end; j += 16) {
        int rid = (j + l16 < end) ? csr[j + l16] : 0;
        int cnt = end - j; if (cnt > 16) cnt = 16;
        int t = 0;
        for (; t + 3 < cnt; t += 4) {
            int r0 = __shfl(rid, sb + t, 64);
            int r1 = __shfl(rid, sb + t + 1, 64);
            int r2 = __shfl(rid, sb + t + 2, 64);
            int r3 = __shfl(rid, sb + t + 3, 64);
            float4 v0 = *(const float4*)(h1p + ((size_t)r0 << 6) + fl);
            float4 v1 = *(const float4*)(h1p + ((size_t)r1 << 6) + fl);
            float4 v2 = *(const float4*)(h1p + ((size_t)r2 << 6) + fl);
            float4 v3 = *(const float4*)(h1p + ((size_t)r3 << 6) + fl);
            acc.x += (v0.x + v1.x) + (v2.x + v3.x);
            acc.y += (v0.y + v1.y) + (v2.y + v3.y);
            acc.z += (v0.z + v1.z) + (v2.z + v3.z);
            acc.w += (v0.w + v1.w) + (v2.w + v3.w);
        }
        for (; t < cnt; ++t) {
            int r = __shfl(rid, sb + t, 64);
            float4 v = *(const float4*)(h1p + ((size_t)r << 6) + fl);
            acc.x += v.x; acc.y += v.y; acc.z += v.z; acc.w += v.w;
        }
    }
    float dn = dinv[nd];
    float4 bb = *(const float4*)(b1 + fl);
    float4 gg = *(const float4*)(g1 + fl);
    float4 ee = *(const float4*)(be1 + fl);
    float4 mm = *(const float4*)(rm1 + fl);
    float4 vv = *(const float4*)(rv1 + fl);
    float4 o;
    o.x = fmaxf((dn * acc.x + bb.x - mm.x) * (gg.x * rsqrtf(vv.x + BN_EPS)) + ee.x, 0.f);
    o.y = fmaxf((dn * acc.y + bb.y - mm.y) * (gg.y * rsqrtf(vv.y + BN_EPS)) + ee.y, 0.f);
    o.z = fmaxf((dn * acc.z + bb.z - mm.z) * (gg.z * rsqrtf(vv.z + BN_EPS)) + ee.z, 0.f);
    o.w = fmaxf((dn * acc.w + bb.w - mm.w) * (gg.w * rsqrtf(vv.w + BN_EPS)) + ee.w, 0.f);
    if (nd0 < N) *(float4*)(hact + ((size_t)nd0 << 6) + fl) = o;
}

// ---------- gather layer 2: 8 nodes/wave, lane owns 4 features + fused FC ----------
__global__ __launch_bounds__(256) void k_gather2(const float* __restrict__ h2p, const int* __restrict__ offs,
                                                 const int* __restrict__ csr, const float* __restrict__ dinv,
                                                 const float* __restrict__ b2, const float* __restrict__ g2,
                                                 const float* __restrict__ be2, const float* __restrict__ rm2,
                                                 const float* __restrict__ rv2, const float* __restrict__ fcW,
                                                 const float* __restrict__ fcb, float* __restrict__ out, int N) {
    int wid = (blockIdx.x * 256 + threadIdx.x) >> 6;
    int lane = threadIdx.x & 63;
    int sub = lane >> 3;              // node slot 0..7
    int l8 = lane & 7;
    int fl = l8 << 2;                 // feature base 0..28
    int nd0 = wid * 8 + sub;
    int nd = (nd0 < N) ? nd0 : N - 1;
    int start = offs[nd], end = offs[nd + 1];
    float4 acc = *(const float4*)(h2p + ((size_t)nd << 5) + fl);   // self loop
    int sb = sub << 3;
    for (int j = start; j < end; j += 8) {
        int rid = (j + l8 < end) ? csr[j + l8] : 0;
        int cnt = end - j; if (cnt > 8) cnt = 8;
        int t = 0;
        for (; t + 3 < cnt; t += 4) {
            int r0 = __shfl(rid, sb + t, 64);
            int r1 = __shfl(rid, sb + t + 1, 64);
            int r2 = __shfl(rid, sb + t + 2, 64);
            int r3 = __shfl(rid, sb + t + 3, 64);
            float4 v0 = *(const float4*)(h2p + ((size_t)r0 << 5) + fl);
            float4 v1 = *(const float4*)(h2p + ((size_t)r1 << 5) + fl);
            float4 v2 = *(const float4*)(h2p + ((size_t)r2 << 5) + fl);
            float4 v3 = *(const float4*)(h2p + ((size_t)r3 << 5) + fl);
            acc.x += (v0.x + v1.x) + (v2.x + v3.x);
            acc.y += (v0.y + v1.y) + (v2.y + v3.y);
            acc.z += (v0.z + v1.z) + (v2.z + v3.z);
            acc.w += (v0.w + v1.w) + (v2.w + v3.w);
        }
        for (; t < cnt; ++t) {
            int r = __shfl(rid, sb + t, 64);
            float4 v = *(const float4*)(h2p + ((size_t)r << 5) + fl);
            acc.x += v.x; acc.y += v.y; acc.z += v.z; acc.w += v.w;
        }
    }
    float dn = dinv[nd];
    float4 bb = *(const float4*)(b2 + fl);
    float4 gg = *(const float4*)(g2 + fl);
    float4 ee = *(const float4*)(be2 + fl);
    float4 mm = *(const float4*)(rm2 + fl);
    float4 vv = *(const float4*)(rv2 + fl);
    float4 ww = *(const float4*)(fcW + fl);
    float s;
    s  = fmaxf((dn * acc.x + bb.x - mm.x) * (gg.x * rsqrtf(vv.x + BN_EPS)) + ee.x, 0.f) * ww.x;
    s += fmaxf((dn * acc.y + bb.y - mm.y) * (gg.y * rsqrtf(vv.y + BN_EPS)) + ee.y, 0.f) * ww.y;
    s += fmaxf((dn * acc.z + bb.z - mm.z) * (gg.z * rsqrtf(vv.z + BN_EPS)) + ee.z, 0.f) * ww.z;
    s += fmaxf((dn * acc.w + bb.w - mm.w) * (gg.w * rsqrtf(vv.w + BN_EPS)) + ee.w, 0.f) * ww.w;
    s += __shfl_down(s, 4, 8);
    s += __shfl_down(s, 2, 8);
    s += __shfl_down(s, 1, 8);
    if (nd0 < N && l8 == 0) out[nd0] = s + fcb[0];
}

extern "C" void kernel_launch(void* const* d_in, const int* in_sizes, int n_in,
                              void* d_out, int out_size, void* d_ws, size_t ws_size,
                              hipStream_t stream) {
    const float* x   = (const float*)d_in[0];
    const int*   ei  = (const int*)d_in[1];
    const float* W1  = (const float*)d_in[2];
    const float* b1  = (const float*)d_in[3];
    const float* W2  = (const float*)d_in[4];
    const float* b2  = (const float*)d_in[5];
    const float* fcW = (const float*)d_in[6];
    const float* fcb = (const float*)d_in[7];
    const float* g1  = (const float*)d_in[8];
    const float* be1 = (const float*)d_in[9];
    const float* rm1 = (const float*)d_in[10];
    const float* rv1 = (const float*)d_in[11];
    const float* g2  = (const float*)d_in[12];
    const float* be2 = (const float*)d_in[13];
    const float* rm2 = (const float*)d_in[14];
    const float* rv2 = (const float*)d_in[15];
    float* out = (float*)d_out;

    const int N = N_NODES, E = N_EDGES;
    const int NB = (N + 255) / 256;          // 196 scan blocks

    char* base = (char*)d_ws;
    int*   deg    = (int*)(base);                        // N ints
    int*   offs   = (int*)(base + 200704);               // N+1 ints
    int*   cursor = (int*)(base + 2 * 200704);           // N ints
    float* dinv   = (float*)(base + 3 * 200704);         // N floats
    int*   bsum   = (int*)(base + 4 * 200704);
    int*   bofs   = (int*)(base + 4 * 200704 + 1024);
    int*   csr    = (int*)(base + 4 * 200704 + 2048);                        // E ints
    float* h1p    = (float*)(base + 4 * 200704 + 2048 + 3200000);            // N*64
    float* hact   = (float*)(base + 4 * 200704 + 2048 + 3200000 + 12800000); // N*64
    float* h2p    = h1p;   // h1p dead after gather1

    hipMemsetAsync(deg, 0, (size_t)N * sizeof(int), stream);

    k_deg  <<<(E + 255) / 256, 256, 0, stream>>>(ei, deg, E);
    k_scan1<<<NB, 256, 0, stream>>>(deg, bsum, dinv, N);
    k_scan2<<<1, 256, 0, stream>>>(bsum, bofs, offs, NB, N);
    k_scan3<<<NB, 256, 0, stream>>>(deg, bofs, offs, cursor, N);
    k_fill <<<(E + 255) / 256, 256, 0, stream>>>(ei, cursor, csr, E);

    k_gemm<IN_CH, HID><<<(N + 31) / 32, 256, 0, stream>>>(x, W1, dinv, h1p, N);
    k_gather1<<<((N + 3) / 4 * 64 + 255) / 256, 256, 0, stream>>>(h1p, offs, csr, dinv, b1, g1, be1, rm1, rv1, hact, N);
    k_gemm<HID, HID2><<<(N + 63) / 64, 256, 0, stream>>>(hact, W2, dinv, h2p, N);
    k_gather2<<<((N + 7) / 8 * 64 + 255) / 256, 256, 0, stream>>>(h2p, offs, csr, dinv, b2, g2, be2, rm2, rv2, fcW, fcb, out, N);
}

// Round 4
// 272.100 us; speedup vs baseline: 1.9445x; 1.1725x over previous
//
#include <hip/hip_runtime.h>

#define N_NODES 50000
#define N_EDGES 800000
#define IN_CH 128
#define HID 64
#define HID2 32
#define BN_EPS 1e-5f

// ---------- degree ----------
__global__ __launch_bounds__(256) void k_deg(const int* __restrict__ ei, int* __restrict__ deg, int E) {
    int e = blockIdx.x * 256 + threadIdx.x;
    if (e < E) atomicAdd(&deg[ei[E + e]], 1);
}

// ---------- scan stage 1 (block sums) + dinv ----------
__global__ __launch_bounds__(256) void k_scan1(const int* __restrict__ deg, int* __restrict__ bsum,
                                               float* __restrict__ dinv, int N) {
    __shared__ int s[256];
    int i = blockIdx.x * 256 + threadIdx.x;
    int d = (i < N) ? deg[i] : 0;
    if (i < N) dinv[i] = rsqrtf((float)d + 1.0f);  // +1 = self loop
    s[threadIdx.x] = d;
    __syncthreads();
    for (int off = 128; off > 0; off >>= 1) {
        if (threadIdx.x < off) s[threadIdx.x] += s[threadIdx.x + off];
        __syncthreads();
    }
    if (threadIdx.x == 0) bsum[blockIdx.x] = s[0];
}

__global__ __launch_bounds__(256) void k_scan2(const int* __restrict__ bsum, int* __restrict__ bofs,
                                               int* __restrict__ offs, int NB, int N) {
    __shared__ int s[256];
    int t = threadIdx.x;
    int v = (t < NB) ? bsum[t] : 0;
    s[t] = v; __syncthreads();
    for (int off = 1; off < 256; off <<= 1) {
        int u = (t >= off) ? s[t - off] : 0;
        __syncthreads(); s[t] += u; __syncthreads();
    }
    if (t < NB) bofs[t] = s[t] - v;          // exclusive
    if (t == NB - 1) offs[N] = s[t];         // total == E
}

__global__ __launch_bounds__(256) void k_scan3(const int* __restrict__ deg, const int* __restrict__ bofs,
                                               int* __restrict__ offs, int* __restrict__ cursor, int N) {
    __shared__ int s[256];
    int i = blockIdx.x * 256 + threadIdx.x, t = threadIdx.x;
    int v = (i < N) ? deg[i] : 0;
    s[t] = v; __syncthreads();
    for (int off = 1; off < 256; off <<= 1) {
        int u = (t >= off) ? s[t - off] : 0;
        __syncthreads(); s[t] += u; __syncthreads();
    }
    if (i < N) {
        int ex = bofs[blockIdx.x] + s[t] - v;
        offs[i] = ex; cursor[i] = ex;
    }
}

// ---------- CSR fill ----------
__global__ __launch_bounds__(256) void k_fill(const int* __restrict__ ei, int* __restrict__ cursor,
                                              int* __restrict__ csr, int E) {
    int e = blockIdx.x * 256 + threadIdx.x;
    if (e >= E) return;
    int r = ei[e], c = ei[E + e];
    int pos = atomicAdd(&cursor[c], 1);
    csr[pos] = r;
}

// ---------- LDS-tiled GEMM: outp[n][f] = dinv[n] * sum_k in[n][k]*W[k][f] ----------
// BM nodes/block, 256 threads, each thread = 4 nodes x 4 features.
// A-tile stride AS padded so rows 4 apart land 16 banks apart (2-way = free).
template <int BM, int KD, int FD, int AS>
__global__ __launch_bounds__(256) void k_gemm(const float* __restrict__ in, const float* __restrict__ W,
                                              const float* __restrict__ dinv, float* __restrict__ outp, int N) {
    __shared__ float As[BM * AS];
    __shared__ float Ws[KD * FD];
    int tid = threadIdx.x;
    int n0 = blockIdx.x * BM;
    // stage A-tile: coalesced float4 loads, rewritten into padded LDS rows
    const int TOT4 = BM * KD / 4;
    const int K4 = KD / 4;
#pragma unroll
    for (int idx = tid; idx < TOT4; idx += 256) {
        int r = idx / K4, c = idx % K4;
        int n = n0 + r; if (n > N - 1) n = N - 1;         // clamp (store masked)
        float4 v = *(const float4*)(in + (size_t)n * KD + c * 4);
        *(float4*)(As + r * AS + c * 4) = v;
    }
    // stage W (contiguous)
    const int WT4 = KD * FD / 4;
#pragma unroll
    for (int idx = tid; idx < WT4; idx += 256) {
        *(float4*)(Ws + idx * 4) = *(const float4*)(W + idx * 4);
    }
    __syncthreads();
    const int NFG = FD / 4;                 // f-groups
    int tn = tid % NFG, tm = tid / NFG;
    int na = tm * 4, fb = tn * 4;
    float acc[4][4] = {};
#pragma unroll 4
    for (int k = 0; k < KD; k += 4) {
        float4 a[4], b[4];
#pragma unroll
        for (int i = 0; i < 4; ++i) a[i] = *(const float4*)(As + (na + i) * AS + k);
#pragma unroll
        for (int j = 0; j < 4; ++j) b[j] = *(const float4*)(Ws + (k + j) * FD + fb);
#pragma unroll
        for (int i = 0; i < 4; ++i) {
            acc[i][0] = fmaf(a[i].x, b[0].x, acc[i][0]);
            acc[i][1] = fmaf(a[i].x, b[0].y, acc[i][1]);
            acc[i][2] = fmaf(a[i].x, b[0].z, acc[i][2]);
            acc[i][3] = fmaf(a[i].x, b[0].w, acc[i][3]);
            acc[i][0] = fmaf(a[i].y, b[1].x, acc[i][0]);
            acc[i][1] = fmaf(a[i].y, b[1].y, acc[i][1]);
            acc[i][2] = fmaf(a[i].y, b[1].z, acc[i][2]);
            acc[i][3] = fmaf(a[i].y, b[1].w, acc[i][3]);
            acc[i][0] = fmaf(a[i].z, b[2].x, acc[i][0]);
            acc[i][1] = fmaf(a[i].z, b[2].y, acc[i][1]);
            acc[i][2] = fmaf(a[i].z, b[2].z, acc[i][2]);
            acc[i][3] = fmaf(a[i].z, b[2].w, acc[i][3]);
            acc[i][0] = fmaf(a[i].w, b[3].x, acc[i][0]);
            acc[i][1] = fmaf(a[i].w, b[3].y, acc[i][1]);
            acc[i][2] = fmaf(a[i].w, b[3].z, acc[i][2]);
            acc[i][3] = fmaf(a[i].w, b[3].w, acc[i][3]);
        }
    }
#pragma unroll
    for (int i = 0; i < 4; ++i) {
        int n = n0 + na + i;
        if (n < N) {
            float dn = dinv[n];
            float4 o = make_float4(acc[i][0] * dn, acc[i][1] * dn, acc[i][2] * dn, acc[i][3] * dn);
            *(float4*)(outp + (size_t)n * FD + fb) = o;
        }
    }
}

// ---------- gather layer 1: 4 nodes/wave, lane owns 4 features (float4) ----------
__global__ __launch_bounds__(256) void k_gather1(const float* __restrict__ h1p, const int* __restrict__ offs,
                                                 const int* __restrict__ csr, const float* __restrict__ dinv,
                                                 const float* __restrict__ b1, const float* __restrict__ g1,
                                                 const float* __restrict__ be1, const float* __restrict__ rm1,
                                                 const float* __restrict__ rv1, float* __restrict__ hact, int N) {
    int wid = (blockIdx.x * 256 + threadIdx.x) >> 6;
    int lane = threadIdx.x & 63;
    int sub = lane >> 4;              // node slot 0..3
    int l16 = lane & 15;
    int fl = l16 << 2;                // feature base
    int nd0 = wid * 4 + sub;
    int nd = (nd0 < N) ? nd0 : N - 1;
    int start = offs[nd], end = offs[nd + 1];
    float4 acc = *(const float4*)(h1p + ((size_t)nd << 6) + fl);   // self loop
    int sb = sub << 4;
    for (int j = start; j < end; j += 16) {
        int rid = (j + l16 < end) ? csr[j + l16] : 0;
        int cnt = end - j; if (cnt > 16) cnt = 16;
        int t = 0;
        for (; t + 3 < cnt; t += 4) {
            int r0 = __shfl(rid, sb + t, 64);
            int r1 = __shfl(rid, sb + t + 1, 64);
            int r2 = __shfl(rid, sb + t + 2, 64);
            int r3 = __shfl(rid, sb + t + 3, 64);
            float4 v0 = *(const float4*)(h1p + ((size_t)r0 << 6) + fl);
            float4 v1 = *(const float4*)(h1p + ((size_t)r1 << 6) + fl);
            float4 v2 = *(const float4*)(h1p + ((size_t)r2 << 6) + fl);
            float4 v3 = *(const float4*)(h1p + ((size_t)r3 << 6) + fl);
            acc.x += (v0.x + v1.x) + (v2.x + v3.x);
            acc.y += (v0.y + v1.y) + (v2.y + v3.y);
            acc.z += (v0.z + v1.z) + (v2.z + v3.z);
            acc.w += (v0.w + v1.w) + (v2.w + v3.w);
        }
        for (; t < cnt; ++t) {
            int r = __shfl(rid, sb + t, 64);
            float4 v = *(const float4*)(h1p + ((size_t)r << 6) + fl);
            acc.x += v.x; acc.y += v.y; acc.z += v.z; acc.w += v.w;
        }
    }
    float dn = dinv[nd];
    float4 bb = *(const float4*)(b1 + fl);
    float4 gg = *(const float4*)(g1 + fl);
    float4 ee = *(const float4*)(be1 + fl);
    float4 mm = *(const float4*)(rm1 + fl);
    float4 vv = *(const float4*)(rv1 + fl);
    float4 o;
    o.x = fmaxf((dn * acc.x + bb.x - mm.x) * (gg.x * rsqrtf(vv.x + BN_EPS)) + ee.x, 0.f);
    o.y = fmaxf((dn * acc.y + bb.y - mm.y) * (gg.y * rsqrtf(vv.y + BN_EPS)) + ee.y, 0.f);
    o.z = fmaxf((dn * acc.z + bb.z - mm.z) * (gg.z * rsqrtf(vv.z + BN_EPS)) + ee.z, 0.f);
    o.w = fmaxf((dn * acc.w + bb.w - mm.w) * (gg.w * rsqrtf(vv.w + BN_EPS)) + ee.w, 0.f);
    if (nd0 < N) *(float4*)(hact + ((size_t)nd0 << 6) + fl) = o;
}

// ---------- gather layer 2: 8 nodes/wave, lane owns 4 features + fused FC ----------
__global__ __launch_bounds__(256) void k_gather2(const float* __restrict__ h2p, const int* __restrict__ offs,
                                                 const int* __restrict__ csr, const float* __restrict__ dinv,
                                                 const float* __restrict__ b2, const float* __restrict__ g2,
                                                 const float* __restrict__ be2, const float* __restrict__ rm2,
                                                 const float* __restrict__ rv2, const float* __restrict__ fcW,
                                                 const float* __restrict__ fcb, float* __restrict__ out, int N) {
    int wid = (blockIdx.x * 256 + threadIdx.x) >> 6;
    int lane = threadIdx.x & 63;
    int sub = lane >> 3;              // node slot 0..7
    int l8 = lane & 7;
    int fl = l8 << 2;                 // feature base 0..28
    int nd0 = wid * 8 + sub;
    int nd = (nd0 < N) ? nd0 : N - 1;
    int start = offs[nd], end = offs[nd + 1];
    float4 acc = *(const float4*)(h2p + ((size_t)nd << 5) + fl);   // self loop
    int sb = sub << 3;
    for (int j = start; j < end; j += 8) {
        int rid = (j + l8 < end) ? csr[j + l8] : 0;
        int cnt = end - j; if (cnt > 8) cnt = 8;
        int t = 0;
        for (; t + 3 < cnt; t += 4) {
            int r0 = __shfl(rid, sb + t, 64);
            int r1 = __shfl(rid, sb + t + 1, 64);
            int r2 = __shfl(rid, sb + t + 2, 64);
            int r3 = __shfl(rid, sb + t + 3, 64);
            float4 v0 = *(const float4*)(h2p + ((size_t)r0 << 5) + fl);
            float4 v1 = *(const float4*)(h2p + ((size_t)r1 << 5) + fl);
            float4 v2 = *(const float4*)(h2p + ((size_t)r2 << 5) + fl);
            float4 v3 = *(const float4*)(h2p + ((size_t)r3 << 5) + fl);
            acc.x += (v0.x + v1.x) + (v2.x + v3.x);
            acc.y += (v0.y + v1.y) + (v2.y + v3.y);
            acc.z += (v0.z + v1.z) + (v2.z + v3.z);
            acc.w += (v0.w + v1.w) + (v2.w + v3.w);
        }
        for (; t < cnt; ++t) {
            int r = __shfl(rid, sb + t, 64);
            float4 v = *(const float4*)(h2p + ((size_t)r << 5) + fl);
            acc.x += v.x; acc.y += v.y; acc.z += v.z; acc.w += v.w;
        }
    }
    float dn = dinv[nd];
    float4 bb = *(const float4*)(b2 + fl);
    float4 gg = *(const float4*)(g2 + fl);
    float4 ee = *(const float4*)(be2 + fl);
    float4 mm = *(const float4*)(rm2 + fl);
    float4 vv = *(const float4*)(rv2 + fl);
    float4 ww = *(const float4*)(fcW + fl);
    float s;
    s  = fmaxf((dn * acc.x + bb.x - mm.x) * (gg.x * rsqrtf(vv.x + BN_EPS)) + ee.x, 0.f) * ww.x;
    s += fmaxf((dn * acc.y + bb.y - mm.y) * (gg.y * rsqrtf(vv.y + BN_EPS)) + ee.y, 0.f) * ww.y;
    s += fmaxf((dn * acc.z + bb.z - mm.z) * (gg.z * rsqrtf(vv.z + BN_EPS)) + ee.z, 0.f) * ww.z;
    s += fmaxf((dn * acc.w + bb.w - mm.w) * (gg.w * rsqrtf(vv.w + BN_EPS)) + ee.w, 0.f) * ww.w;
    s += __shfl_down(s, 4, 8);
    s += __shfl_down(s, 2, 8);
    s += __shfl_down(s, 1, 8);
    if (nd0 < N && l8 == 0) out[nd0] = s + fcb[0];
}

extern "C" void kernel_launch(void* const* d_in, const int* in_sizes, int n_in,
                              void* d_out, int out_size, void* d_ws, size_t ws_size,
                              hipStream_t stream) {
    const float* x   = (const float*)d_in[0];
    const int*   ei  = (const int*)d_in[1];
    const float* W1  = (const float*)d_in[2];
    const float* b1  = (const float*)d_in[3];
    const float* W2  = (const float*)d_in[4];
    const float* b2  = (const float*)d_in[5];
    const float* fcW = (const float*)d_in[6];
    const float* fcb = (const float*)d_in[7];
    const float* g1  = (const float*)d_in[8];
    const float* be1 = (const float*)d_in[9];
    const float* rm1 = (const float*)d_in[10];
    const float* rv1 = (const float*)d_in[11];
    const float* g2  = (const float*)d_in[12];
    const float* be2 = (const float*)d_in[13];
    const float* rm2 = (const float*)d_in[14];
    const float* rv2 = (const float*)d_in[15];
    float* out = (float*)d_out;

    const int N = N_NODES, E = N_EDGES;
    const int NB = (N + 255) / 256;          // 196 scan blocks

    char* base = (char*)d_ws;
    int*   deg    = (int*)(base);                        // N ints
    int*   offs   = (int*)(base + 200704);               // N+1 ints
    int*   cursor = (int*)(base + 2 * 200704);           // N ints
    float* dinv   = (float*)(base + 3 * 200704);         // N floats
    int*   bsum   = (int*)(base + 4 * 200704);
    int*   bofs   = (int*)(base + 4 * 200704 + 1024);
    int*   csr    = (int*)(base + 4 * 200704 + 2048);                        // E ints
    float* h1p    = (float*)(base + 4 * 200704 + 2048 + 3200000);            // N*64
    float* hact   = (float*)(base + 4 * 200704 + 2048 + 3200000 + 12800000); // N*64
    float* h2p    = h1p;   // h1p dead after gather1

    hipMemsetAsync(deg, 0, (size_t)N * sizeof(int), stream);

    k_deg  <<<(E + 255) / 256, 256, 0, stream>>>(ei, deg, E);
    k_scan1<<<NB, 256, 0, stream>>>(deg, bsum, dinv, N);
    k_scan2<<<1, 256, 0, stream>>>(bsum, bofs, offs, NB, N);
    k_scan3<<<NB, 256, 0, stream>>>(deg, bofs, offs, cursor, N);
    k_fill <<<(E + 255) / 256, 256, 0, stream>>>(ei, cursor, csr, E);

    // Layer 1: BM=64, K=128, F=64, A-stride 132 (rows 4 apart -> +16 banks)
    k_gemm<64, IN_CH, HID, 132><<<(N + 63) / 64, 256, 0, stream>>>(x, W1, dinv, h1p, N);
    k_gather1<<<((N + 3) / 4 * 64 + 255) / 256, 256, 0, stream>>>(h1p, offs, csr, dinv, b1, g1, be1, rm1, rv1, hact, N);
    // Layer 2: BM=128, K=64, F=32, A-stride 68
    k_gemm<128, HID, HID2, 68><<<(N + 127) / 128, 256, 0, stream>>>(hact, W2, dinv, h2p, N);
    k_gather2<<<((N + 7) / 8 * 64 + 255) / 256, 256, 0, stream>>>(h2p, offs, csr, dinv, b2, g2, be2, rm2, rv2, fcW, fcb, out, N);
}

// Round 5
// 228.788 us; speedup vs baseline: 2.3127x; 1.1893x over previous
//
#include <hip/hip_runtime.h>

#define N_NODES 50000
#define N_EDGES 800000
#define IN_CH 128
#define HID 64
#define HID2 32
#define BN_EPS 1e-5f

// ---------- degree + per-edge rank (one atomic pass, coalesced rank store) ----------
__global__ __launch_bounds__(256) void k_degrank(const int* __restrict__ ei, int* __restrict__ deg,
                                                 int* __restrict__ rank, int E) {
    int t = blockIdx.x * 256 + threadIdx.x;
    int e = t * 4;
    if (e >= E) return;
    int4 c4 = *(const int4*)(ei + E + e);
    int4 rk;
    rk.x = atomicAdd(&deg[c4.x], 1);
    rk.y = atomicAdd(&deg[c4.y], 1);
    rk.z = atomicAdd(&deg[c4.z], 1);
    rk.w = atomicAdd(&deg[c4.w], 1);
    *(int4*)(rank + e) = rk;
}

// ---------- scan stage 1 (block sums) + dinv ----------
__global__ __launch_bounds__(256) void k_scan1(const int* __restrict__ deg, int* __restrict__ bsum,
                                               float* __restrict__ dinv, int N) {
    __shared__ int s[256];
    int i = blockIdx.x * 256 + threadIdx.x;
    int d = (i < N) ? deg[i] : 0;
    if (i < N) dinv[i] = rsqrtf((float)d + 1.0f);  // +1 = self loop
    s[threadIdx.x] = d;
    __syncthreads();
    for (int off = 128; off > 0; off >>= 1) {
        if (threadIdx.x < off) s[threadIdx.x] += s[threadIdx.x + off];
        __syncthreads();
    }
    if (threadIdx.x == 0) bsum[blockIdx.x] = s[0];
}

__global__ __launch_bounds__(256) void k_scan2(const int* __restrict__ bsum, int* __restrict__ bofs,
                                               int* __restrict__ offs, int NB, int N) {
    __shared__ int s[256];
    int t = threadIdx.x;
    int v = (t < NB) ? bsum[t] : 0;
    s[t] = v; __syncthreads();
    for (int off = 1; off < 256; off <<= 1) {
        int u = (t >= off) ? s[t - off] : 0;
        __syncthreads(); s[t] += u; __syncthreads();
    }
    if (t < NB) bofs[t] = s[t] - v;          // exclusive
    if (t == NB - 1) offs[N] = s[t];         // total == E
}

__global__ __launch_bounds__(256) void k_scan3(const int* __restrict__ deg, const int* __restrict__ bofs,
                                               int* __restrict__ offs, int N) {
    __shared__ int s[256];
    int i = blockIdx.x * 256 + threadIdx.x, t = threadIdx.x;
    int v = (i < N) ? deg[i] : 0;
    s[t] = v; __syncthreads();
    for (int off = 1; off < 256; off <<= 1) {
        int u = (t >= off) ? s[t - off] : 0;
        __syncthreads(); s[t] += u; __syncthreads();
    }
    if (i < N) offs[i] = bofs[blockIdx.x] + s[t] - v;
}

// ---------- CSR fill, atomic-free: csr[offs[c]+rank[e]] = row ----------
__global__ __launch_bounds__(256) void k_fillr(const int* __restrict__ ei, const int* __restrict__ rank,
                                               const int* __restrict__ offs, int* __restrict__ csr, int E) {
    int t = blockIdx.x * 256 + threadIdx.x;
    int e = t * 4;
    if (e >= E) return;
    int4 r4 = *(const int4*)(ei + e);
    int4 c4 = *(const int4*)(ei + E + e);
    int4 k4 = *(const int4*)(rank + e);
    csr[offs[c4.x] + k4.x] = r4.x;
    csr[offs[c4.y] + k4.y] = r4.y;
    csr[offs[c4.z] + k4.z] = r4.z;
    csr[offs[c4.w] + k4.w] = r4.w;
}

// ---------- LDS-tiled GEMM: outp[n][f] = dinv[n] * sum_k in[n][k]*W[k][f] ----------
template <int BM, int KD, int FD, int AS>
__global__ __launch_bounds__(256) void k_gemm(const float* __restrict__ in, const float* __restrict__ W,
                                              const float* __restrict__ dinv, float* __restrict__ outp, int N) {
    __shared__ float As[BM * AS];
    __shared__ float Ws[KD * FD];
    int tid = threadIdx.x;
    int n0 = blockIdx.x * BM;
    const int TOT4 = BM * KD / 4;
    const int K4 = KD / 4;
#pragma unroll
    for (int idx = tid; idx < TOT4; idx += 256) {
        int r = idx / K4, c = idx % K4;
        int n = n0 + r; if (n > N - 1) n = N - 1;
        float4 v = *(const float4*)(in + (size_t)n * KD + c * 4);
        *(float4*)(As + r * AS + c * 4) = v;
    }
    const int WT4 = KD * FD / 4;
#pragma unroll
    for (int idx = tid; idx < WT4; idx += 256) {
        *(float4*)(Ws + idx * 4) = *(const float4*)(W + idx * 4);
    }
    __syncthreads();
    const int NFG = FD / 4;
    int tn = tid % NFG, tm = tid / NFG;
    int na = tm * 4, fb = tn * 4;
    float acc[4][4] = {};
#pragma unroll 4
    for (int k = 0; k < KD; k += 4) {
        float4 a[4], b[4];
#pragma unroll
        for (int i = 0; i < 4; ++i) a[i] = *(const float4*)(As + (na + i) * AS + k);
#pragma unroll
        for (int j = 0; j < 4; ++j) b[j] = *(const float4*)(Ws + (k + j) * FD + fb);
#pragma unroll
        for (int i = 0; i < 4; ++i) {
            acc[i][0] = fmaf(a[i].x, b[0].x, acc[i][0]);
            acc[i][1] = fmaf(a[i].x, b[0].y, acc[i][1]);
            acc[i][2] = fmaf(a[i].x, b[0].z, acc[i][2]);
            acc[i][3] = fmaf(a[i].x, b[0].w, acc[i][3]);
            acc[i][0] = fmaf(a[i].y, b[1].x, acc[i][0]);
            acc[i][1] = fmaf(a[i].y, b[1].y, acc[i][1]);
            acc[i][2] = fmaf(a[i].y, b[1].z, acc[i][2]);
            acc[i][3] = fmaf(a[i].y, b[1].w, acc[i][3]);
            acc[i][0] = fmaf(a[i].z, b[2].x, acc[i][0]);
            acc[i][1] = fmaf(a[i].z, b[2].y, acc[i][1]);
            acc[i][2] = fmaf(a[i].z, b[2].z, acc[i][2]);
            acc[i][3] = fmaf(a[i].z, b[2].w, acc[i][3]);
            acc[i][0] = fmaf(a[i].w, b[3].x, acc[i][0]);
            acc[i][1] = fmaf(a[i].w, b[3].y, acc[i][1]);
            acc[i][2] = fmaf(a[i].w, b[3].z, acc[i][2]);
            acc[i][3] = fmaf(a[i].w, b[3].w, acc[i][3]);
        }
    }
#pragma unroll
    for (int i = 0; i < 4; ++i) {
        int n = n0 + na + i;
        if (n < N) {
            float dn = dinv[n];
            float4 o = make_float4(acc[i][0] * dn, acc[i][1] * dn, acc[i][2] * dn, acc[i][3] * dn);
            *(float4*)(outp + (size_t)n * FD + fb) = o;
        }
    }
}

// ---------- gather layer 1: 4 nodes/wave, lane owns 4 features (float4) ----------
__global__ __launch_bounds__(256) void k_gather1(const float* __restrict__ h1p, const int* __restrict__ offs,
                                                 const int* __restrict__ csr, const float* __restrict__ dinv,
                                                 const float* __restrict__ b1, const float* __restrict__ g1,
                                                 const float* __restrict__ be1, const float* __restrict__ rm1,
                                                 const float* __restrict__ rv1, float* __restrict__ hact, int N) {
    int wid = (blockIdx.x * 256 + threadIdx.x) >> 6;
    int lane = threadIdx.x & 63;
    int sub = lane >> 4;              // node slot 0..3
    int l16 = lane & 15;
    int fl = l16 << 2;                // feature base
    int nd0 = wid * 4 + sub;
    int nd = (nd0 < N) ? nd0 : N - 1;
    int start = offs[nd], end = offs[nd + 1];
    float4 acc = *(const float4*)(h1p + ((size_t)nd << 6) + fl);   // self loop
    int sb = sub << 4;
    for (int j = start; j < end; j += 16) {
        int rid = (j + l16 < end) ? csr[j + l16] : 0;
        int cnt = end - j; if (cnt > 16) cnt = 16;
        int t = 0;
        for (; t + 3 < cnt; t += 4) {
            int r0 = __shfl(rid, sb + t, 64);
            int r1 = __shfl(rid, sb + t + 1, 64);
            int r2 = __shfl(rid, sb + t + 2, 64);
            int r3 = __shfl(rid, sb + t + 3, 64);
            float4 v0 = *(const float4*)(h1p + ((size_t)r0 << 6) + fl);
            float4 v1 = *(const float4*)(h1p + ((size_t)r1 << 6) + fl);
            float4 v2 = *(const float4*)(h1p + ((size_t)r2 << 6) + fl);
            float4 v3 = *(const float4*)(h1p + ((size_t)r3 << 6) + fl);
            acc.x += (v0.x + v1.x) + (v2.x + v3.x);
            acc.y += (v0.y + v1.y) + (v2.y + v3.y);
            acc.z += (v0.z + v1.z) + (v2.z + v3.z);
            acc.w += (v0.w + v1.w) + (v2.w + v3.w);
        }
        for (; t < cnt; ++t) {
            int r = __shfl(rid, sb + t, 64);
            float4 v = *(const float4*)(h1p + ((size_t)r << 6) + fl);
            acc.x += v.x; acc.y += v.y; acc.z += v.z; acc.w += v.w;
        }
    }
    float dn = dinv[nd];
    float4 bb = *(const float4*)(b1 + fl);
    float4 gg = *(const float4*)(g1 + fl);
    float4 ee = *(const float4*)(be1 + fl);
    float4 mm = *(const float4*)(rm1 + fl);
    float4 vv = *(const float4*)(rv1 + fl);
    float4 o;
    o.x = fmaxf((dn * acc.x + bb.x - mm.x) * (gg.x * rsqrtf(vv.x + BN_EPS)) + ee.x, 0.f);
    o.y = fmaxf((dn * acc.y + bb.y - mm.y) * (gg.y * rsqrtf(vv.y + BN_EPS)) + ee.y, 0.f);
    o.z = fmaxf((dn * acc.z + bb.z - mm.z) * (gg.z * rsqrtf(vv.z + BN_EPS)) + ee.z, 0.f);
    o.w = fmaxf((dn * acc.w + bb.w - mm.w) * (gg.w * rsqrtf(vv.w + BN_EPS)) + ee.w, 0.f);
    if (nd0 < N) *(float4*)(hact + ((size_t)nd0 << 6) + fl) = o;
}

// ---------- gather layer 2: 8 nodes/wave, lane owns 4 features + fused FC ----------
__global__ __launch_bounds__(256) void k_gather2(const float* __restrict__ h2p, const int* __restrict__ offs,
                                                 const int* __restrict__ csr, const float* __restrict__ dinv,
                                                 const float* __restrict__ b2, const float* __restrict__ g2,
                                                 const float* __restrict__ be2, const float* __restrict__ rm2,
                                                 const float* __restrict__ rv2, const float* __restrict__ fcW,
                                                 const float* __restrict__ fcb, float* __restrict__ out, int N) {
    int wid = (blockIdx.x * 256 + threadIdx.x) >> 6;
    int lane = threadIdx.x & 63;
    int sub = lane >> 3;              // node slot 0..7
    int l8 = lane & 7;
    int fl = l8 << 2;                 // feature base 0..28
    int nd0 = wid * 8 + sub;
    int nd = (nd0 < N) ? nd0 : N - 1;
    int start = offs[nd], end = offs[nd + 1];
    float4 acc = *(const float4*)(h2p + ((size_t)nd << 5) + fl);   // self loop
    int sb = sub << 3;
    for (int j = start; j < end; j += 8) {
        int rid = (j + l8 < end) ? csr[j + l8] : 0;
        int cnt = end - j; if (cnt > 8) cnt = 8;
        int t = 0;
        for (; t + 3 < cnt; t += 4) {
            int r0 = __shfl(rid, sb + t, 64);
            int r1 = __shfl(rid, sb + t + 1, 64);
            int r2 = __shfl(rid, sb + t + 2, 64);
            int r3 = __shfl(rid, sb + t + 3, 64);
            float4 v0 = *(const float4*)(h2p + ((size_t)r0 << 5) + fl);
            float4 v1 = *(const float4*)(h2p + ((size_t)r1 << 5) + fl);
            float4 v2 = *(const float4*)(h2p + ((size_t)r2 << 5) + fl);
            float4 v3 = *(const float4*)(h2p + ((size_t)r3 << 5) + fl);
            acc.x += (v0.x + v1.x) + (v2.x + v3.x);
            acc.y += (v0.y + v1.y) + (v2.y + v3.y);
            acc.z += (v0.z + v1.z) + (v2.z + v3.z);
            acc.w += (v0.w + v1.w) + (v2.w + v3.w);
        }
        for (; t < cnt; ++t) {
            int r = __shfl(rid, sb + t, 64);
            float4 v = *(const float4*)(h2p + ((size_t)r << 5) + fl);
            acc.x += v.x; acc.y += v.y; acc.z += v.z; acc.w += v.w;
        }
    }
    float dn = dinv[nd];
    float4 bb = *(const float4*)(b2 + fl);
    float4 gg = *(const float4*)(g2 + fl);
    float4 ee = *(const float4*)(be2 + fl);
    float4 mm = *(const float4*)(rm2 + fl);
    float4 vv = *(const float4*)(rv2 + fl);
    float4 ww = *(const float4*)(fcW + fl);
    float s;
    s  = fmaxf((dn * acc.x + bb.x - mm.x) * (gg.x * rsqrtf(vv.x + BN_EPS)) + ee.x, 0.f) * ww.x;
    s += fmaxf((dn * acc.y + bb.y - mm.y) * (gg.y * rsqrtf(vv.y + BN_EPS)) + ee.y, 0.f) * ww.y;
    s += fmaxf((dn * acc.z + bb.z - mm.z) * (gg.z * rsqrtf(vv.z + BN_EPS)) + ee.z, 0.f) * ww.z;
    s += fmaxf((dn * acc.w + bb.w - mm.w) * (gg.w * rsqrtf(vv.w + BN_EPS)) + ee.w, 0.f) * ww.w;
    s += __shfl_down(s, 4, 8);
    s += __shfl_down(s, 2, 8);
    s += __shfl_down(s, 1, 8);
    if (nd0 < N && l8 == 0) out[nd0] = s + fcb[0];
}

extern "C" void kernel_launch(void* const* d_in, const int* in_sizes, int n_in,
                              void* d_out, int out_size, void* d_ws, size_t ws_size,
                              hipStream_t stream) {
    const float* x   = (const float*)d_in[0];
    const int*   ei  = (const int*)d_in[1];
    const float* W1  = (const float*)d_in[2];
    const float* b1  = (const float*)d_in[3];
    const float* W2  = (const float*)d_in[4];
    const float* b2  = (const float*)d_in[5];
    const float* fcW = (const float*)d_in[6];
    const float* fcb = (const float*)d_in[7];
    const float* g1  = (const float*)d_in[8];
    const float* be1 = (const float*)d_in[9];
    const float* rm1 = (const float*)d_in[10];
    const float* rv1 = (const float*)d_in[11];
    const float* g2  = (const float*)d_in[12];
    const float* be2 = (const float*)d_in[13];
    const float* rm2 = (const float*)d_in[14];
    const float* rv2 = (const float*)d_in[15];
    float* out = (float*)d_out;

    const int N = N_NODES, E = N_EDGES;
    const int NB = (N + 255) / 256;          // 196 scan blocks

    char* base = (char*)d_ws;
    int*   deg  = (int*)(base);                          // N ints
    int*   offs = (int*)(base + 200704);                 // N+1 ints
    float* dinv = (float*)(base + 401408);               // N floats
    int*   bsum = (int*)(base + 602112);                 // 256 ints
    int*   bofs = (int*)(base + 603136);                 // 256 ints
    int*   rank = (int*)(base + 604160);                 // E ints (3.2 MB)
    int*   csr  = (int*)(base + 3804160);                // E ints (3.2 MB)
    float* h1p  = (float*)(base + 7004160);              // N*64 (12.8 MB)
    float* hact = (float*)(base + 19804160);             // N*64 (12.8 MB)
    float* h2p  = h1p;   // h1p dead after gather1

    hipMemsetAsync(deg, 0, (size_t)N * sizeof(int), stream);

    k_degrank<<<(E / 4 + 255) / 256, 256, 0, stream>>>(ei, deg, rank, E);
    k_scan1<<<NB, 256, 0, stream>>>(deg, bsum, dinv, N);
    k_scan2<<<1, 256, 0, stream>>>(bsum, bofs, offs, NB, N);
    k_scan3<<<NB, 256, 0, stream>>>(deg, bofs, offs, N);
    k_fillr<<<(E / 4 + 255) / 256, 256, 0, stream>>>(ei, rank, offs, csr, E);

    // Layer 1: BM=64, K=128, F=64, A-stride 132
    k_gemm<64, IN_CH, HID, 132><<<(N + 63) / 64, 256, 0, stream>>>(x, W1, dinv, h1p, N);
    k_gather1<<<((N + 3) / 4 * 64 + 255) / 256, 256, 0, stream>>>(h1p, offs, csr, dinv, b1, g1, be1, rm1, rv1, hact, N);
    // Layer 2: BM=128, K=64, F=32, A-stride 68
    k_gemm<128, HID, HID2, 68><<<(N + 127) / 128, 256, 0, stream>>>(hact, W2, dinv, h2p, N);
    k_gather2<<<((N + 7) / 8 * 64 + 255) / 256, 256, 0, stream>>>(h2p, offs, csr, dinv, b2, g2, be2, rm2, rv2, fcW, fcb, out, N);
}